// Round 1
// baseline (1974.773 us; speedup 1.0000x reference)
//
#include <hip/hip_runtime.h>
#include <cstdint>
#include <math.h>

#define B_SZ 512
#define K_SZ 1024
#define N_INTV 5
#define D_U 32
#define D_H 64
#define SEL_OUT (D_H * D_U + D_H + 1) /* 2113 */

// ---------------- Phase 1: per-event (b,k) parallel work ----------------
// Computes Bu[b,k,h] (h innermost, coalesced for phase 2) and x[b,k] = dt*delta.
__global__ __launch_bounds__(256) void im_phase1(
    const float* __restrict__ t_int, const float* __restrict__ U_int,
    const float* __restrict__ Wp, const float* __restrict__ bp,
    const float* __restrict__ gamma, const float* __restrict__ beta,
    const float* __restrict__ Bmat, const float* __restrict__ Ws,
    const float* __restrict__ bs,
    float* __restrict__ Bu, float* __restrict__ xbuf)
{
    int idx = blockIdx.x * blockDim.x + threadIdx.x;
    if (idx >= B_SZ * K_SZ) return;
    int k = idx & (K_SZ - 1);

    // Load the 5 intervention features for this event.
    float Uin[N_INTV];
    #pragma unroll
    for (int c = 0; c < N_INTV; ++c)
        Uin[c] = U_int[(size_t)idx * N_INTV + c];

    // Projection 5 -> 32 (Wp is wave-uniform -> scalar loads).
    float u[D_U];
    #pragma unroll
    for (int d = 0; d < D_U; ++d) {
        float acc = bp[d];
        #pragma unroll
        for (int c = 0; c < N_INTV; ++c)
            acc = fmaf(Wp[d * N_INTV + c], Uin[c], acc);
        u[d] = acc;
    }

    // LayerNorm over D_U (population variance, eps inside rsqrt).
    float mu = 0.f;
    #pragma unroll
    for (int d = 0; d < D_U; ++d) mu += u[d];
    mu *= (1.f / D_U);
    float m2 = 0.f;
    #pragma unroll
    for (int d = 0; d < D_U; ++d) { float t = u[d] - mu; m2 += t * t; }
    float rs = rsqrtf(m2 * (1.f / D_U) + 1e-5f);
    #pragma unroll
    for (int d = 0; d < D_U; ++d)
        u[d] = (u[d] - mu) * rs * gamma[d] + beta[d];

    // delta = softplus(last row of sel); only row SEL_OUT-1 of Ws is needed.
    {
        const float* wr = Ws + (size_t)(SEL_OUT - 1) * D_U;
        float s = bs[SEL_OUT - 1];
        #pragma unroll
        for (int j = 0; j < D_U; ++j) s = fmaf(wr[j], u[j], s);
        float sp = fmaxf(s, 0.f) + log1pf(expf(-fabsf(s)));
        float dt = 0.f;
        if (k > 0) dt = fmaxf(t_int[idx] - t_int[idx - 1], 0.f);
        xbuf[idx] = dt * sp;
    }

    // Bu[h] = sum_i (Bmat[h,i] + dB[h,i]) * u[i],
    // dB[h,i] = bs[h*32+i] + Ws[h*32+i,:] . u   (all weights wave-uniform).
    float* bo = Bu + (size_t)idx * D_H;
    #pragma unroll 1
    for (int h = 0; h < D_H; ++h) {
        float acc = 0.f;
        #pragma unroll
        for (int i = 0; i < D_U; ++i) {
            const float* wr = Ws + (size_t)(h * D_U + i) * D_U;
            float d = bs[h * D_U + i];
            #pragma unroll
            for (int j = 0; j < D_U; ++j) d = fmaf(wr[j], u[j], d);
            acc = fmaf(Bmat[h * D_U + i] + d, u[i], acc);
        }
        bo[h] = acc;
    }
}

// ---------------- Phase 2: sequential scan over k, parallel over (b,h) ----
// One wave (64 lanes = 64 h-channels) per batch row. 16-deep double-buffered
// prefetch of Bu/x keeps enough loads in flight to hide HBM latency at the
// low (2 waves/CU) occupancy this phase has.
#define CH 16
__global__ __launch_bounds__(64) void im_phase2(
    const float* __restrict__ h0, const float* __restrict__ t_int,
    const int* __restrict__ int_lens, const float* __restrict__ A_log,
    const float* __restrict__ Bu, const float* __restrict__ xbuf,
    float* __restrict__ out)
{
    int b = blockIdx.x;
    int h = threadIdx.x;

    float A = -expf(A_log[h]);
    float invA = 1.f / A;
    float hv = h0[b * D_H + h];

    float* h_final = out;                                   // (B, D_H)
    float* times   = out + (size_t)B_SZ * D_H;              // (K+1, B)
    float* states  = times + (size_t)(K_SZ + 1) * B_SZ;     // (K+1, B, D_H)

    states[(size_t)b * D_H + h] = hv;                       // states[0,b,h] = h0
    if (h == 0) times[b] = t_int[(size_t)b * K_SZ];         // times[0,b] = t[b,0]

    int len = int_lens[b];
    const float* bup = Bu + (size_t)b * K_SZ * D_H;
    const float* xp  = xbuf + (size_t)b * K_SZ;

    float buA[CH], buB[CH], xA[CH], xB[CH];
    #pragma unroll
    for (int c = 0; c < CH; ++c) {
        buA[c] = bup[(size_t)c * D_H + h];
        xA[c]  = xp[c];
    }

    for (int kc = 0; kc < K_SZ; kc += CH) {
        if (kc + CH < K_SZ) {
            #pragma unroll
            for (int c = 0; c < CH; ++c) {
                buB[c] = bup[(size_t)(kc + CH + c) * D_H + h];
                xB[c]  = xp[kc + CH + c];
            }
        }
        #pragma unroll
        for (int c = 0; c < CH; ++c) {
            int k = kc + c;
            float Ab = expf(A * xA[c]);                      // x >= 0 -> Ab <= 1
            float hn = fmaf(Ab, hv, (Ab - 1.f) * invA * buA[c]);
            hv = (k < len) ? hn : hv;
            states[((size_t)(k + 1) * B_SZ + b) * D_H + h] = hv;
            if (h == 0) times[(size_t)(k + 1) * B_SZ + b] = t_int[(size_t)b * K_SZ + k];
        }
        #pragma unroll
        for (int c = 0; c < CH; ++c) { buA[c] = buB[c]; xA[c] = xB[c]; }
    }

    h_final[b * D_H + h] = hv;
}

extern "C" void kernel_launch(void* const* d_in, const int* in_sizes, int n_in,
                              void* d_out, int out_size, void* d_ws, size_t ws_size,
                              hipStream_t stream) {
    const float* h0       = (const float*)d_in[0];
    const float* t_int    = (const float*)d_in[1];
    const float* U_int    = (const float*)d_in[2];
    const int*   int_lens = (const int*)d_in[3];
    const float* Wp       = (const float*)d_in[4];
    const float* bp       = (const float*)d_in[5];
    const float* gamma    = (const float*)d_in[6];
    const float* beta     = (const float*)d_in[7];
    const float* A_log    = (const float*)d_in[8];
    const float* Bmat     = (const float*)d_in[9];
    const float* Ws       = (const float*)d_in[10];
    const float* bs       = (const float*)d_in[11];

    float* out = (float*)d_out;
    float* Bu   = (float*)d_ws;                                    // B*K*D_H f32
    float* xbuf = (float*)((char*)d_ws + (size_t)B_SZ * K_SZ * D_H * sizeof(float));

    dim3 g1((B_SZ * K_SZ + 255) / 256), b1(256);
    im_phase1<<<g1, b1, 0, stream>>>(t_int, U_int, Wp, bp, gamma, beta,
                                     Bmat, Ws, bs, Bu, xbuf);

    dim3 g2(B_SZ), b2(64);
    im_phase2<<<g2, b2, 0, stream>>>(h0, t_int, int_lens, A_log, Bu, xbuf, out);
}

// Round 2
// 416.318 us; speedup vs baseline: 4.7434x; 4.7434x over previous
//
#include <hip/hip_runtime.h>
#include <cstdint>
#include <math.h>

#define B_SZ 512
#define K_SZ 1024
#define N_INTV 5
#define D_U 32
#define D_H 64
#define SEL_OUT (D_H * D_U + D_H + 1) /* 2113 */

#define KP 1056           /* 1024 quadratic + 32 linear = 33 * 32 */
#define WROW 1064         /* padded LDS row (bf16): 532 dwords, 532/4=133 odd -> conflict-free b128 */
#define NTILES (B_SZ * K_SZ / 16)   /* 32768 wave-tiles of 16 events */
#define P1_BLOCKS 256
#define P1_THREADS 512    /* 8 waves */

typedef __attribute__((ext_vector_type(8))) short bf16x8;
typedef __attribute__((ext_vector_type(4))) float f32x4;

__device__ inline uint16_t f2bf_rne(float f) {
    uint32_t u = __builtin_bit_cast(uint32_t, f);
    uint32_t r = (u + 0x7FFFu + ((u >> 16) & 1u)) >> 16;
    return (uint16_t)r;
}
// pack two fp32 -> bf16x2 dword by byte-perm truncation (1 VALU per pair)
__device__ inline uint32_t pack_bf16_trunc(float lo, float hi) {
    return __builtin_amdgcn_perm(__builtin_bit_cast(uint32_t, hi),
                                 __builtin_bit_cast(uint32_t, lo), 0x07060302u);
}

// ---------------- Phase 1: MFMA quadratic-form GEMM --------------------
// Bu[e][h] = sum_i (Bmat[h,i]+bs[h*32+i]) u_i + sum_{i,j} Ws[h*32+i][j] u_i u_j
// = p(e) . W[h], p = [u (x) u (1024) | u (32)], K = 1056.
__global__ __launch_bounds__(P1_THREADS, 1) void im_phase1(
    const float* __restrict__ t_int, const float* __restrict__ U_int,
    const float* __restrict__ Wp, const float* __restrict__ bp,
    const float* __restrict__ gamma, const float* __restrict__ beta,
    const float* __restrict__ Bmat, const float* __restrict__ Ws,
    const float* __restrict__ bs,
    float* __restrict__ Bu, float* __restrict__ xbuf)
{
    extern __shared__ uint16_t Wl[];   // [D_H][WROW] bf16
    const int tid = threadIdx.x;

    // ---- stage W into LDS (once per block; 256 persistent blocks) ----
    for (int n = 0; n < D_H; ++n) {
        for (int k = tid; k < WROW; k += P1_THREADS) {
            float v;
            if (k < 1024) {
                int i = k >> 5, j = k & 31;
                v = Ws[(size_t)(n * D_U + i) * D_U + j];
            } else if (k < KP) {
                int i = k - 1024;
                v = Bmat[n * D_U + i] + bs[n * D_U + i];
            } else {
                v = 0.f;
            }
            Wl[n * WROW + k] = f2bf_rne(v);
        }
    }
    __syncthreads();

    const int wid  = tid >> 6;
    const int lane = tid & 63;
    const int lrow = lane & 15;   // A-operand M-row / B-operand N-col
    const int g    = lane >> 4;   // k-group

    // B-frag base pointers for the 4 N-tiles (h = nf*16 + lrow)
    const uint16_t* w0 = Wl + (size_t)(0 * 16 + lrow) * WROW + g * 8;
    const uint16_t* w1 = Wl + (size_t)(1 * 16 + lrow) * WROW + g * 8;
    const uint16_t* w2 = Wl + (size_t)(2 * 16 + lrow) * WROW + g * 8;
    const uint16_t* w3 = Wl + (size_t)(3 * 16 + lrow) * WROW + g * 8;

    for (int tile = blockIdx.x * 8 + wid; tile < NTILES; tile += P1_BLOCKS * 8) {
        const int base = tile << 4;
        const int ev   = base + lrow;   // this lane's event (4x redundant across g)

        // ---- load U (5 feats), project 5->32, layernorm ----
        float Uin[N_INTV];
        #pragma unroll
        for (int c = 0; c < N_INTV; ++c)
            Uin[c] = U_int[(size_t)ev * N_INTV + c];

        float u[D_U];
        #pragma unroll
        for (int d = 0; d < D_U; ++d) {
            float acc = bp[d];
            #pragma unroll
            for (int c = 0; c < N_INTV; ++c)
                acc = fmaf(Wp[d * N_INTV + c], Uin[c], acc);
            u[d] = acc;
        }
        float mu = 0.f;
        #pragma unroll
        for (int d = 0; d < D_U; ++d) mu += u[d];
        mu *= (1.f / D_U);
        float m2 = 0.f;
        #pragma unroll
        for (int d = 0; d < D_U; ++d) { float t = u[d] - mu; m2 += t * t; }
        float rs = rsqrtf(m2 * (1.f / D_U) + 1e-5f);
        #pragma unroll
        for (int d = 0; d < D_U; ++d)
            u[d] = (u[d] - mu) * rs * gamma[d] + beta[d];

        // ---- delta/x for phase 2 (one lane-group per event) ----
        if (g == 0) {
            const float* wr = Ws + (size_t)(SEL_OUT - 1) * D_U;
            float s = bs[SEL_OUT - 1];
            #pragma unroll
            for (int j = 0; j < D_U; ++j) s = fmaf(wr[j], u[j], s);
            float sp = fmaxf(s, 0.f) + log1pf(expf(-fabsf(s)));
            int k = ev & (K_SZ - 1);
            float dtv = 0.f;
            if (k > 0) dtv = fmaxf(t_int[ev] - t_int[ev - 1], 0.f);
            xbuf[ev] = dtv * sp;
        }

        // ---- this lane's static 8-slice of u (k-group g) ----
        float u8[8];
        if (g == 0) {
            #pragma unroll
            for (int j = 0; j < 8; ++j) u8[j] = u[j];
        } else if (g == 1) {
            #pragma unroll
            for (int j = 0; j < 8; ++j) u8[j] = u[8 + j];
        } else if (g == 2) {
            #pragma unroll
            for (int j = 0; j < 8; ++j) u8[j] = u[16 + j];
        } else {
            #pragma unroll
            for (int j = 0; j < 8; ++j) u8[j] = u[24 + j];
        }

        // ---- K-loop: 32 quadratic steps + 1 linear step ----
        f32x4 acc0 = {0.f, 0.f, 0.f, 0.f};
        f32x4 acc1 = {0.f, 0.f, 0.f, 0.f};
        f32x4 acc2 = {0.f, 0.f, 0.f, 0.f};
        f32x4 acc3 = {0.f, 0.f, 0.f, 0.f};

        union AF { uint32_t w[4]; bf16x8 v; };

        #pragma unroll
        for (int t = 0; t < 32; ++t) {
            AF af;
            float ut = u[t];
            af.w[0] = pack_bf16_trunc(ut * u8[0], ut * u8[1]);
            af.w[1] = pack_bf16_trunc(ut * u8[2], ut * u8[3]);
            af.w[2] = pack_bf16_trunc(ut * u8[4], ut * u8[5]);
            af.w[3] = pack_bf16_trunc(ut * u8[6], ut * u8[7]);
            bf16x8 b0 = *(const bf16x8*)(w0 + t * 32);
            bf16x8 b1 = *(const bf16x8*)(w1 + t * 32);
            bf16x8 b2 = *(const bf16x8*)(w2 + t * 32);
            bf16x8 b3 = *(const bf16x8*)(w3 + t * 32);
            acc0 = __builtin_amdgcn_mfma_f32_16x16x32_bf16(af.v, b0, acc0, 0, 0, 0);
            acc1 = __builtin_amdgcn_mfma_f32_16x16x32_bf16(af.v, b1, acc1, 0, 0, 0);
            acc2 = __builtin_amdgcn_mfma_f32_16x16x32_bf16(af.v, b2, acc2, 0, 0, 0);
            acc3 = __builtin_amdgcn_mfma_f32_16x16x32_bf16(af.v, b3, acc3, 0, 0, 0);
        }
        {   // linear tail (k = 1024..1055): p = u
            AF af;
            af.w[0] = pack_bf16_trunc(u8[0], u8[1]);
            af.w[1] = pack_bf16_trunc(u8[2], u8[3]);
            af.w[2] = pack_bf16_trunc(u8[4], u8[5]);
            af.w[3] = pack_bf16_trunc(u8[6], u8[7]);
            bf16x8 b0 = *(const bf16x8*)(w0 + 1024);
            bf16x8 b1 = *(const bf16x8*)(w1 + 1024);
            bf16x8 b2 = *(const bf16x8*)(w2 + 1024);
            bf16x8 b3 = *(const bf16x8*)(w3 + 1024);
            acc0 = __builtin_amdgcn_mfma_f32_16x16x32_bf16(af.v, b0, acc0, 0, 0, 0);
            acc1 = __builtin_amdgcn_mfma_f32_16x16x32_bf16(af.v, b1, acc1, 0, 0, 0);
            acc2 = __builtin_amdgcn_mfma_f32_16x16x32_bf16(af.v, b2, acc2, 0, 0, 0);
            acc3 = __builtin_amdgcn_mfma_f32_16x16x32_bf16(af.v, b3, acc3, 0, 0, 0);
        }

        // ---- C store: event = base + g*4 + r, h = nf*16 + lrow ----
        float* bo = Bu + (size_t)base * D_H;
        #pragma unroll
        for (int r = 0; r < 4; ++r) {
            int erow = (g * 4 + r) * D_H;
            bo[erow +  0 + lrow] = acc0[r];
            bo[erow + 16 + lrow] = acc1[r];
            bo[erow + 32 + lrow] = acc2[r];
            bo[erow + 48 + lrow] = acc3[r];
        }
    }
}

// ---------------- Phase 2: sequential scan over k, parallel over (b,h) ----
#define CH 16
__global__ __launch_bounds__(64) void im_phase2(
    const float* __restrict__ h0, const float* __restrict__ t_int,
    const int* __restrict__ int_lens, const float* __restrict__ A_log,
    const float* __restrict__ Bu, const float* __restrict__ xbuf,
    float* __restrict__ out)
{
    int b = blockIdx.x;
    int h = threadIdx.x;

    float A = -expf(A_log[h]);
    float invA = 1.f / A;
    float hv = h0[b * D_H + h];

    float* h_final = out;                                   // (B, D_H)
    float* times   = out + (size_t)B_SZ * D_H;              // (K+1, B)
    float* states  = times + (size_t)(K_SZ + 1) * B_SZ;     // (K+1, B, D_H)

    states[(size_t)b * D_H + h] = hv;
    if (h == 0) times[b] = t_int[(size_t)b * K_SZ];

    int len = int_lens[b];
    const float* bup = Bu + (size_t)b * K_SZ * D_H;
    const float* xp  = xbuf + (size_t)b * K_SZ;

    float buA[CH], buB[CH], xA[CH], xB[CH];
    #pragma unroll
    for (int c = 0; c < CH; ++c) {
        buA[c] = bup[(size_t)c * D_H + h];
        xA[c]  = xp[c];
    }

    for (int kc = 0; kc < K_SZ; kc += CH) {
        if (kc + CH < K_SZ) {
            #pragma unroll
            for (int c = 0; c < CH; ++c) {
                buB[c] = bup[(size_t)(kc + CH + c) * D_H + h];
                xB[c]  = xp[kc + CH + c];
            }
        }
        #pragma unroll
        for (int c = 0; c < CH; ++c) {
            int k = kc + c;
            float Ab = expf(A * xA[c]);
            float hn = fmaf(Ab, hv, (Ab - 1.f) * invA * buA[c]);
            hv = (k < len) ? hn : hv;
            states[((size_t)(k + 1) * B_SZ + b) * D_H + h] = hv;
            if (h == 0) times[(size_t)(k + 1) * B_SZ + b] = t_int[(size_t)b * K_SZ + k];
        }
        #pragma unroll
        for (int c = 0; c < CH; ++c) { buA[c] = buB[c]; xA[c] = xB[c]; }
    }

    h_final[b * D_H + h] = hv;
}

extern "C" void kernel_launch(void* const* d_in, const int* in_sizes, int n_in,
                              void* d_out, int out_size, void* d_ws, size_t ws_size,
                              hipStream_t stream) {
    const float* h0       = (const float*)d_in[0];
    const float* t_int    = (const float*)d_in[1];
    const float* U_int    = (const float*)d_in[2];
    const int*   int_lens = (const int*)d_in[3];
    const float* Wp       = (const float*)d_in[4];
    const float* bp       = (const float*)d_in[5];
    const float* gamma    = (const float*)d_in[6];
    const float* beta     = (const float*)d_in[7];
    const float* A_log    = (const float*)d_in[8];
    const float* Bmat     = (const float*)d_in[9];
    const float* Ws       = (const float*)d_in[10];
    const float* bs       = (const float*)d_in[11];

    float* out = (float*)d_out;
    float* Bu   = (float*)d_ws;                                    // B*K*D_H f32
    float* xbuf = (float*)((char*)d_ws + (size_t)B_SZ * K_SZ * D_H * sizeof(float));

    size_t lds_bytes = (size_t)D_H * WROW * sizeof(uint16_t);      // 136192
    im_phase1<<<dim3(P1_BLOCKS), dim3(P1_THREADS), lds_bytes, stream>>>(
        t_int, U_int, Wp, bp, gamma, beta, Bmat, Ws, bs, Bu, xbuf);

    im_phase2<<<dim3(B_SZ), dim3(64), 0, stream>>>(h0, t_int, int_lens, A_log, Bu, xbuf, out);
}